// Round 3
// baseline (1614.040 us; speedup 1.0000x reference)
//
#include <hip/hip_runtime.h>
#include <hip/hip_bf16.h>
#include <cstdint>

// ---------------------------------------------------------------------------
// Edge2NodeProp via counting-sort CSR + fused gather/MLP.
//   A: histogram of idx_i                 (counts in L2, 400KB)
//   B: single-block scan -> offsets+cursor (counts aliases cursor: read-first)
//   C: scatter edge ids into CSR order    (edge_order 5MB, stays in L2)
//   D: per-node gather + gate + sum + 3xDense/Swish + Dense->1
// All f32 buffers; idx int32; out (N,1) f32.
// ---------------------------------------------------------------------------

__global__ __launch_bounds__(256) void hist_kernel(
    const int* __restrict__ idx, int* __restrict__ counts, int n_edges)
{
    int e = blockIdx.x * 256 + threadIdx.x;
    const int stride = gridDim.x * 256;
    for (; e < n_edges; e += stride) {
        atomicAdd(&counts[idx[e]], 1);
    }
}

// counts may ALIAS cursor: each counts[i] is read exactly once, before the
// (only) write to cursor[i].
__global__ __launch_bounds__(1024) void scan_kernel(
    const int* __restrict__ counts,
    int* __restrict__ offsets,   // n+1 (distinct buffer)
    int* __restrict__ cursor,    // n   (may alias counts)
    int n)
{
    __shared__ int sdata[1024];
    const int t = threadIdx.x;
    const int chunk = (n + 1023) >> 10;
    const int lo = t * chunk;
    const int hi = min(lo + chunk, n);

    int s = 0;
    for (int i = lo; i < hi; ++i) s += counts[i];

    sdata[t] = s;
    __syncthreads();
    for (int off = 1; off < 1024; off <<= 1) {
        int v = (t >= off) ? sdata[t - off] : 0;
        __syncthreads();
        sdata[t] += v;
        __syncthreads();
    }
    int running = sdata[t] - s;   // exclusive prefix of this thread's chunk
    for (int i = lo; i < hi; ++i) {
        const int c = counts[i];  // read BEFORE cursor[i] write (aliased)
        offsets[i] = running;
        cursor[i]  = running;
        running += c;
    }
    if (t == 1023) offsets[n] = sdata[1023];
}

__global__ __launch_bounds__(256) void scatter_kernel(
    const int* __restrict__ idx, int* __restrict__ cursor,
    int* __restrict__ edge_order, int n_edges)
{
    int e = blockIdx.x * 256 + threadIdx.x;
    const int stride = gridDim.x * 256;
    for (; e < n_edges; e += stride) {
        const int pos = atomicAdd(&cursor[idx[e]], 1);
        edge_order[pos] = e;
    }
}

__device__ __forceinline__ float mlp_layer(const float* __restrict__ WT,
                                           const float* __restrict__ bias,
                                           float h, int lane)
{
    float acc = bias[lane];
#pragma unroll
    for (int k = 0; k < 64; ++k) {
        const float wk = WT[k * 64 + lane];
        const float hk = __int_as_float(
            __builtin_amdgcn_readlane(__float_as_int(h), k));
        acc = fmaf(wk, hk, acc);
    }
    return acc / (1.0f + __expf(-acc));   // swish
}

__global__ __launch_bounds__(256) void node_fused_kernel(
    const float* __restrict__ x,      // (E,64)
    const float* __restrict__ rbf,    // (E,16)
    const int*   __restrict__ offsets,
    const int*   __restrict__ edge_order,
    const float* __restrict__ Wrbf,   // (64,16)
    const float* __restrict__ W1, const float* __restrict__ b1,
    const float* __restrict__ W2, const float* __restrict__ b2,
    const float* __restrict__ W3, const float* __restrict__ b3,
    const float* __restrict__ Wout,   // (1,64)
    float* __restrict__ out,          // (N,1)
    int n_nodes)
{
    __shared__ float WT[3][64 * 64];  // 48 KiB
    __shared__ float bs[3][64];
    __shared__ float wo[64];

    const int t = threadIdx.x;
    for (int i = t; i < 64 * 64; i += 256) {
        const int d = i & 63;
        const int k = i >> 6;
        WT[0][k * 64 + d] = W1[d * 64 + k];
        WT[1][k * 64 + d] = W2[d * 64 + k];
        WT[2][k * 64 + d] = W3[d * 64 + k];
    }
    if (t < 64) {
        bs[0][t] = b1[t];
        bs[1][t] = b2[t];
        bs[2][t] = b3[t];
        wo[t]    = Wout[t];
    }

    const int lane = t & 63;
    float w[16];
    {
        const float4* wp = (const float4*)(Wrbf + (size_t)lane * 16);
        float4 a = wp[0], b = wp[1], c = wp[2], d = wp[3];
        w[0]=a.x; w[1]=a.y; w[2]=a.z; w[3]=a.w;
        w[4]=b.x; w[5]=b.y; w[6]=b.z; w[7]=b.w;
        w[8]=c.x; w[9]=c.y; w[10]=c.z; w[11]=c.w;
        w[12]=d.x; w[13]=d.y; w[14]=d.z; w[15]=d.w;
    }
    __syncthreads();

    const int wave   = blockIdx.x * (blockDim.x >> 6) + (t >> 6);
    const int nwaves = gridDim.x * (blockDim.x >> 6);

    for (int node = wave; node < n_nodes; node += nwaves) {
        const int start = offsets[node];
        const int end   = offsets[node + 1];

        float acc = 0.0f;
        for (int i = start; i < end; ++i) {
            const int e = edge_order[i];
            const float4* rp = (const float4*)(rbf + (size_t)e * 16);
            float4 r0 = rp[0], r1 = rp[1], r2 = rp[2], r3 = rp[3];
            const float xv = x[(size_t)e * 64 + lane];

            float g = 0.0f;
            g = fmaf(r0.x, w[0], g);  g = fmaf(r0.y, w[1], g);
            g = fmaf(r0.z, w[2], g);  g = fmaf(r0.w, w[3], g);
            g = fmaf(r1.x, w[4], g);  g = fmaf(r1.y, w[5], g);
            g = fmaf(r1.z, w[6], g);  g = fmaf(r1.w, w[7], g);
            g = fmaf(r2.x, w[8], g);  g = fmaf(r2.y, w[9], g);
            g = fmaf(r2.z, w[10], g); g = fmaf(r2.w, w[11], g);
            g = fmaf(r3.x, w[12], g); g = fmaf(r3.y, w[13], g);
            g = fmaf(r3.z, w[14], g); g = fmaf(r3.w, w[15], g);

            acc = fmaf(g, xv, acc);
        }

        float h = acc;
        h = mlp_layer(WT[0], bs[0], h, lane);
        h = mlp_layer(WT[1], bs[1], h, lane);
        h = mlp_layer(WT[2], bs[2], h, lane);

        float v = wo[lane] * h;
#pragma unroll
        for (int off = 32; off >= 1; off >>= 1) v += __shfl_xor(v, off, 64);

        if (lane == 0) out[node] = v;
    }
}

// ---------------------------------------------------------------------------
extern "C" void kernel_launch(void* const* d_in, const int* in_sizes, int n_in,
                              void* d_out, int out_size, void* d_ws, size_t ws_size,
                              hipStream_t stream)
{
    const float* x    = (const float*)d_in[0];
    const float* rbf  = (const float*)d_in[1];
    const int*   idx  = (const int*)d_in[2];
    const float* Wrbf = (const float*)d_in[4];
    const float* W1   = (const float*)d_in[5];
    const float* b1   = (const float*)d_in[6];
    const float* W2   = (const float*)d_in[7];
    const float* b2   = (const float*)d_in[8];
    const float* W3   = (const float*)d_in[9];
    const float* b3   = (const float*)d_in[10];
    const float* Wout = (const float*)d_in[11];

    const int n_edges = in_sizes[0] / 64;
    const int n_nodes = out_size;   // OUT_DIM == 1

    // ws layout (ints): counts/cursor [n], offsets [n+1], edge_order [E]
    int* cursor     = (int*)d_ws;                  // doubles as counts
    int* offsets    = cursor + n_nodes;            // n+1
    int* edge_order = offsets + n_nodes + 1;       // E

    hipMemsetAsync(cursor, 0, (size_t)n_nodes * sizeof(int), stream);

    const int eblocks = (n_edges + 255) / 256;
    hist_kernel<<<eblocks, 256, 0, stream>>>(idx, cursor, n_edges);
    scan_kernel<<<1, 1024, 0, stream>>>(cursor, offsets, cursor, n_nodes);
    scatter_kernel<<<eblocks, 256, 0, stream>>>(idx, cursor, edge_order, n_edges);

    node_fused_kernel<<<768, 256, 0, stream>>>(
        x, rbf, offsets, edge_order, Wrbf,
        W1, b1, W2, b2, W3, b3, Wout, (float*)d_out, n_nodes);
}

// Round 4
// 1047.506 us; speedup vs baseline: 1.5408x; 1.5408x over previous
//
#include <hip/hip_runtime.h>
#include <hip/hip_bf16.h>
#include <cstdint>

// ---------------------------------------------------------------------------
// Edge2NodeProp via counting-sort CSR + high-occupancy gather + node MLP.
//   A: histogram of idx_i
//   B: single-block scan -> offsets + cursor (aliased with counts, read-first)
//   C: scatter edge ids into CSR order
//   D: gather+gate+segment-sum -> hacc (f32, owner-computes, no atomics,
//      no LDS, 4-deep edge ILP, coalesced 64-wide edge-id loads)
//   E: node MLP (LDS-staged transposed weights, readlane broadcast)
// Fallback (ws too small): R3-style fused kernel.
// All f32 buffers; idx int32; out (N,1) f32.
// ---------------------------------------------------------------------------

__global__ __launch_bounds__(256) void hist_kernel(
    const int* __restrict__ idx, int* __restrict__ counts, int n_edges)
{
    int e = blockIdx.x * 256 + threadIdx.x;
    const int stride = gridDim.x * 256;
    for (; e < n_edges; e += stride) {
        atomicAdd(&counts[idx[e]], 1);
    }
}

// counts may alias cursor: counts[i] read exactly once, before cursor[i] write.
__global__ __launch_bounds__(1024) void scan_kernel(
    const int* __restrict__ counts,
    int* __restrict__ offsets,   // n+1 (distinct)
    int* __restrict__ cursor,    // n   (may alias counts)
    int n)
{
    __shared__ int sdata[1024];
    const int t = threadIdx.x;
    const int chunk = (n + 1023) >> 10;
    const int lo = t * chunk;
    const int hi = min(lo + chunk, n);

    int s = 0;
    for (int i = lo; i < hi; ++i) s += counts[i];

    sdata[t] = s;
    __syncthreads();
    for (int off = 1; off < 1024; off <<= 1) {
        int v = (t >= off) ? sdata[t - off] : 0;
        __syncthreads();
        sdata[t] += v;
        __syncthreads();
    }
    int running = sdata[t] - s;
    for (int i = lo; i < hi; ++i) {
        const int c = counts[i];      // read BEFORE aliased write
        offsets[i] = running;
        cursor[i]  = running;
        running += c;
    }
    if (t == 1023) offsets[n] = sdata[1023];
}

__global__ __launch_bounds__(256) void scatter_kernel(
    const int* __restrict__ idx, int* __restrict__ cursor,
    int* __restrict__ edge_order, int n_edges)
{
    int e = blockIdx.x * 256 + threadIdx.x;
    const int stride = gridDim.x * 256;
    for (; e < n_edges; e += stride) {
        const int pos = atomicAdd(&cursor[idx[e]], 1);
        edge_order[pos] = e;
    }
}

// ---------------------------------------------------------------------------
__device__ __forceinline__ float dot16(const float* __restrict__ rp,
                                       const float* __restrict__ w)
{
    const float4* p = (const float4*)rp;
    float4 a = p[0], b = p[1], c = p[2], d = p[3];
    float g = 0.0f;
    g = fmaf(a.x, w[0],  g); g = fmaf(a.y, w[1],  g);
    g = fmaf(a.z, w[2],  g); g = fmaf(a.w, w[3],  g);
    g = fmaf(b.x, w[4],  g); g = fmaf(b.y, w[5],  g);
    g = fmaf(b.z, w[6],  g); g = fmaf(b.w, w[7],  g);
    g = fmaf(c.x, w[8],  g); g = fmaf(c.y, w[9],  g);
    g = fmaf(c.z, w[10], g); g = fmaf(c.w, w[11], g);
    g = fmaf(d.x, w[12], g); g = fmaf(d.y, w[13], g);
    g = fmaf(d.z, w[14], g); g = fmaf(d.w, w[15], g);
    return g;
}

// Kernel D: gather + gate + segment-sum. One wave per node (grid-stride).
// No LDS. Edge ids loaded 64-wide coalesced, readlane'd out, 4-deep ILP.
__global__ __launch_bounds__(256) void gather_kernel(
    const float* __restrict__ x,      // (E,64)
    const float* __restrict__ rbf,    // (E,16)
    const int*   __restrict__ offsets,
    const int*   __restrict__ edge_order,
    const float* __restrict__ Wrbf,   // (64,16)
    float* __restrict__ hacc,         // (N,64)
    int n_nodes)
{
    const int lane   = threadIdx.x & 63;
    const int wave   = blockIdx.x * (blockDim.x >> 6) + (threadIdx.x >> 6);
    const int nwaves = gridDim.x * (blockDim.x >> 6);

    float w[16];
    {
        const float4* wp = (const float4*)(Wrbf + (size_t)lane * 16);
        float4 a = wp[0], b = wp[1], c = wp[2], d = wp[3];
        w[0]=a.x;  w[1]=a.y;  w[2]=a.z;  w[3]=a.w;
        w[4]=b.x;  w[5]=b.y;  w[6]=b.z;  w[7]=b.w;
        w[8]=c.x;  w[9]=c.y;  w[10]=c.z; w[11]=c.w;
        w[12]=d.x; w[13]=d.y; w[14]=d.z; w[15]=d.w;
    }

    for (int node = wave; node < n_nodes; node += nwaves) {
        const int start = offsets[node];
        const int end   = offsets[node + 1];

        float acc = 0.0f;
        int pos = start;
        while (pos < end) {
            const int cnt = min(end - pos, 64);
            // one coalesced load of up to 64 edge ids
            const int myid = (pos + lane < end) ? edge_order[pos + lane] : 0;

            int j = 0;
            for (; j + 4 <= cnt; j += 4) {
                const int e0 = __builtin_amdgcn_readlane(myid, j + 0);
                const int e1 = __builtin_amdgcn_readlane(myid, j + 1);
                const int e2 = __builtin_amdgcn_readlane(myid, j + 2);
                const int e3 = __builtin_amdgcn_readlane(myid, j + 3);

                const float xv0 = x[(size_t)e0 * 64 + lane];
                const float xv1 = x[(size_t)e1 * 64 + lane];
                const float xv2 = x[(size_t)e2 * 64 + lane];
                const float xv3 = x[(size_t)e3 * 64 + lane];

                const float g0 = dot16(rbf + (size_t)e0 * 16, w);
                const float g1 = dot16(rbf + (size_t)e1 * 16, w);
                const float g2 = dot16(rbf + (size_t)e2 * 16, w);
                const float g3 = dot16(rbf + (size_t)e3 * 16, w);

                acc = fmaf(g0, xv0, acc);
                acc = fmaf(g1, xv1, acc);
                acc = fmaf(g2, xv2, acc);
                acc = fmaf(g3, xv3, acc);
            }
            for (; j < cnt; ++j) {
                const int e = __builtin_amdgcn_readlane(myid, j);
                const float xv = x[(size_t)e * 64 + lane];
                acc = fmaf(dot16(rbf + (size_t)e * 16, w), xv, acc);
            }
            pos += cnt;
        }
        hacc[(size_t)node * 64 + lane] = acc;
    }
}

// ---------------------------------------------------------------------------
__device__ __forceinline__ float mlp_layer(const float* __restrict__ WT,
                                           const float* __restrict__ bias,
                                           float h, int lane)
{
    float acc = bias[lane];
#pragma unroll
    for (int k = 0; k < 64; ++k) {
        const float wk = WT[k * 64 + lane];
        const float hk = __int_as_float(
            __builtin_amdgcn_readlane(__float_as_int(h), k));
        acc = fmaf(wk, hk, acc);
    }
    return acc / (1.0f + __expf(-acc));   // swish
}

__global__ __launch_bounds__(256) void node_kernel(
    const float* __restrict__ hacc,   // (N,64)
    const float* __restrict__ W1, const float* __restrict__ b1,
    const float* __restrict__ W2, const float* __restrict__ b2,
    const float* __restrict__ W3, const float* __restrict__ b3,
    const float* __restrict__ Wout,
    float* __restrict__ out,
    int n_nodes)
{
    __shared__ float WT[3][64 * 64];
    __shared__ float bs[3][64];
    __shared__ float wo[64];

    const int t = threadIdx.x;
    for (int i = t; i < 64 * 64; i += 256) {
        const int d = i & 63;
        const int k = i >> 6;
        WT[0][k * 64 + d] = W1[d * 64 + k];
        WT[1][k * 64 + d] = W2[d * 64 + k];
        WT[2][k * 64 + d] = W3[d * 64 + k];
    }
    if (t < 64) {
        bs[0][t] = b1[t];
        bs[1][t] = b2[t];
        bs[2][t] = b3[t];
        wo[t]    = Wout[t];
    }
    __syncthreads();

    const int lane   = t & 63;
    const int wave   = blockIdx.x * (blockDim.x >> 6) + (t >> 6);
    const int nwaves = gridDim.x * (blockDim.x >> 6);

    for (int node = wave; node < n_nodes; node += nwaves) {
        float h = hacc[(size_t)node * 64 + lane];
        h = mlp_layer(WT[0], bs[0], h, lane);
        h = mlp_layer(WT[1], bs[1], h, lane);
        h = mlp_layer(WT[2], bs[2], h, lane);

        float v = wo[lane] * h;
#pragma unroll
        for (int off = 32; off >= 1; off >>= 1) v += __shfl_xor(v, off, 64);

        if (lane == 0) out[node] = v;
    }
}

// ---------------------------------------------------------------------------
// Fallback fused kernel (only used if ws_size can't hold hacc): R3 structure.
__global__ __launch_bounds__(256) void node_fused_kernel(
    const float* __restrict__ x, const float* __restrict__ rbf,
    const int* __restrict__ offsets, const int* __restrict__ edge_order,
    const float* __restrict__ Wrbf,
    const float* __restrict__ W1, const float* __restrict__ b1,
    const float* __restrict__ W2, const float* __restrict__ b2,
    const float* __restrict__ W3, const float* __restrict__ b3,
    const float* __restrict__ Wout,
    float* __restrict__ out, int n_nodes)
{
    __shared__ float WT[3][64 * 64];
    __shared__ float bs[3][64];
    __shared__ float wo[64];

    const int t = threadIdx.x;
    for (int i = t; i < 64 * 64; i += 256) {
        const int d = i & 63;
        const int k = i >> 6;
        WT[0][k * 64 + d] = W1[d * 64 + k];
        WT[1][k * 64 + d] = W2[d * 64 + k];
        WT[2][k * 64 + d] = W3[d * 64 + k];
    }
    if (t < 64) {
        bs[0][t] = b1[t]; bs[1][t] = b2[t]; bs[2][t] = b3[t]; wo[t] = Wout[t];
    }

    const int lane = t & 63;
    float w[16];
    {
        const float4* wp = (const float4*)(Wrbf + (size_t)lane * 16);
        float4 a = wp[0], b = wp[1], c = wp[2], d = wp[3];
        w[0]=a.x;  w[1]=a.y;  w[2]=a.z;  w[3]=a.w;
        w[4]=b.x;  w[5]=b.y;  w[6]=b.z;  w[7]=b.w;
        w[8]=c.x;  w[9]=c.y;  w[10]=c.z; w[11]=c.w;
        w[12]=d.x; w[13]=d.y; w[14]=d.z; w[15]=d.w;
    }
    __syncthreads();

    const int wave   = blockIdx.x * (blockDim.x >> 6) + (t >> 6);
    const int nwaves = gridDim.x * (blockDim.x >> 6);

    for (int node = wave; node < n_nodes; node += nwaves) {
        const int start = offsets[node];
        const int end   = offsets[node + 1];
        float acc = 0.0f;
        int pos = start;
        while (pos < end) {
            const int cnt = min(end - pos, 64);
            const int myid = (pos + lane < end) ? edge_order[pos + lane] : 0;
            for (int j = 0; j < cnt; ++j) {
                const int e = __builtin_amdgcn_readlane(myid, j);
                const float xv = x[(size_t)e * 64 + lane];
                acc = fmaf(dot16(rbf + (size_t)e * 16, w), xv, acc);
            }
            pos += cnt;
        }
        float h = acc;
        h = mlp_layer(WT[0], bs[0], h, lane);
        h = mlp_layer(WT[1], bs[1], h, lane);
        h = mlp_layer(WT[2], bs[2], h, lane);
        float v = wo[lane] * h;
#pragma unroll
        for (int off = 32; off >= 1; off >>= 1) v += __shfl_xor(v, off, 64);
        if (lane == 0) out[node] = v;
    }
}

// ---------------------------------------------------------------------------
extern "C" void kernel_launch(void* const* d_in, const int* in_sizes, int n_in,
                              void* d_out, int out_size, void* d_ws, size_t ws_size,
                              hipStream_t stream)
{
    const float* x    = (const float*)d_in[0];
    const float* rbf  = (const float*)d_in[1];
    const int*   idx  = (const int*)d_in[2];
    const float* Wrbf = (const float*)d_in[4];
    const float* W1   = (const float*)d_in[5];
    const float* b1   = (const float*)d_in[6];
    const float* W2   = (const float*)d_in[7];
    const float* b2   = (const float*)d_in[8];
    const float* W3   = (const float*)d_in[9];
    const float* b3   = (const float*)d_in[10];
    const float* Wout = (const float*)d_in[11];

    const int n_edges = in_sizes[0] / 64;
    const int n_nodes = out_size;

    // ws layout (ints): cursor/counts [n], offsets [n+1], edge_order [E],
    // then hacc [n*64] f32.
    int* cursor     = (int*)d_ws;
    int* offsets    = cursor + n_nodes;
    int* edge_order = offsets + n_nodes + 1;
    float* hacc     = (float*)(edge_order + n_edges);

    const size_t need_sort = (size_t)(2 * n_nodes + 1 + n_edges) * sizeof(int);
    const size_t need_full = need_sort + (size_t)n_nodes * 64 * sizeof(float);

    hipMemsetAsync(cursor, 0, (size_t)n_nodes * sizeof(int), stream);

    const int eblocks = (n_edges + 255) / 256;
    hist_kernel<<<eblocks, 256, 0, stream>>>(idx, cursor, n_edges);
    scan_kernel<<<1, 1024, 0, stream>>>(cursor, offsets, cursor, n_nodes);
    scatter_kernel<<<eblocks, 256, 0, stream>>>(idx, cursor, edge_order, n_edges);

    if (ws_size >= need_full) {
        gather_kernel<<<6144, 256, 0, stream>>>(
            x, rbf, offsets, edge_order, Wrbf, hacc, n_nodes);
        node_kernel<<<2048, 256, 0, stream>>>(
            hacc, W1, b1, W2, b2, W3, b3, Wout, (float*)d_out, n_nodes);
    } else {
        node_fused_kernel<<<768, 256, 0, stream>>>(
            x, rbf, offsets, edge_order, Wrbf,
            W1, b1, W2, b2, W3, b3, Wout, (float*)d_out, n_nodes);
    }
}